// Round 2
// baseline (23049.681 us; speedup 1.0000x reference)
//
#include <hip/hip_runtime.h>
#include <math.h>

#define NBATCH 4
#define DIM    1024
#define NHEAD  4
#define HD     256
#define NQ     1024
#define MASKN  2304           // 48*48
#define NMAX   3329           // 1024 query + 1 sep + 2304 max prompts
#define TWO_PI 6.283185307179586f

typedef unsigned short bf16_t;

__device__ __forceinline__ float gelu_exact(float x) {
    return 0.5f * x * (1.0f + erff(x * 0.70710678118654752f));
}
__device__ __forceinline__ float bf2f(bf16_t h) {
    return __uint_as_float((unsigned)h << 16);
}
__device__ __forceinline__ bf16_t f2bf(float f) {   // round-to-nearest-even
    unsigned u = __float_as_uint(f);
    return (bf16_t)((u + 0x7FFFu + ((u >> 16) & 1u)) >> 16);
}

// ---------------------------------------------------------------- compaction
__global__ __launch_bounds__(256)
void k_compact(const int* __restrict__ mask, int* __restrict__ cnt, int* __restrict__ pidx) {
    int b = blockIdx.x;
    __shared__ int sc;
    if (threadIdx.x == 0) sc = 0;
    __syncthreads();
    for (int c = threadIdx.x; c < MASKN; c += blockDim.x)
        if (mask[b * MASKN + c] > 0) {
            int p = atomicAdd(&sc, 1);
            pidx[b * MASKN + p] = c;
        }
    __syncthreads();
    if (threadIdx.x == 0) cnt[b] = sc;
}

__global__ __launch_bounds__(256)
void k_zerobias(float* __restrict__ z) {
    z[blockIdx.x * 256 + threadIdx.x] = 0.f;
}

// ------------------------------------------------- query tokens: emb + PE (f32 X)
__global__ __launch_bounds__(256)
void k_init_query(const float* __restrict__ emb, const float* __restrict__ gauss,
                  float* __restrict__ X) {
    int b = blockIdx.y, n = blockIdx.x, t = threadIdx.x;
    float fx = 2.0f * (((n & 31) + 0.5f) / 32.0f) - 1.0f;   // x from col
    float fy = 2.0f * (((n >> 5) + 0.5f) / 32.0f) - 1.0f;   // y from row
    const float* e = emb + ((size_t)b * NQ + n) * DIM;
    float* x = X + ((size_t)b * NMAX + n) * DIM;
    for (int d = t; d < 512; d += 256) {
        float ang = TWO_PI * (fx * gauss[d] + fy * gauss[512 + d]);
        float sn, cs; sincosf(ang, &sn, &cs);
        x[d]       = e[d] + sn;
        x[d + 512] = e[d + 512] + cs;
    }
}

// --------------------------------- prompt hidden: gelu(d*w1+b1) (M x 512) bf16
__global__ __launch_bounds__(256)
void k_prompt_h(const float* __restrict__ depth, const float* __restrict__ w1,
                const float* __restrict__ b1, const int* __restrict__ cnt,
                const int* __restrict__ pidx, bf16_t* __restrict__ Hp) {
    int b = blockIdx.y, s = blockIdx.x, t = threadIdx.x;
    bf16_t* hp = Hp + ((size_t)b * MASKN + s) * 512;
    if (s >= cnt[b]) { hp[t] = 0; hp[t + 256] = 0; return; }
    int cell = pidx[b * MASKN + s];
    float d = depth[b * MASKN + cell];
    for (int j = t; j < 512; j += 256)
        hp[j] = f2bf(gelu_exact(fmaf(d, w1[j], b1[j])));
}

// ------------------------------------------ add prompt PE into X rows (f32)
__global__ __launch_bounds__(256)
void k_pe_prompt(const float* __restrict__ gauss, const int* __restrict__ cnt,
                 const int* __restrict__ pidx, float* __restrict__ X) {
    int b = blockIdx.y, s = blockIdx.x, t = threadIdx.x;
    if (s >= cnt[b]) return;
    int cell = pidx[b * MASKN + s];
    int r = cell / 48, c = cell % 48;
    float fx = 2.0f * ((c + 0.5f) / 48.0f) - 1.0f;
    float fy = 2.0f * ((r + 0.5f) / 48.0f) - 1.0f;
    float* x = X + ((size_t)b * NMAX + 1025 + s) * DIM;
    for (int d = t; d < 512; d += 256) {
        float ang = TWO_PI * (fx * gauss[d] + fy * gauss[512 + d]);
        float sn, cs; sincosf(ang, &sn, &cs);
        x[d]       += sn;
        x[d + 512] += cs;
    }
}

// ---------------------------------------------------------------- sep token
__global__ __launch_bounds__(256)
void k_sep(float* __restrict__ X, const float* __restrict__ sep) {
    int b = blockIdx.x, t = threadIdx.x;
    float* x = X + ((size_t)b * NMAX + 1024) * DIM;
    *(float4*)&x[t * 4] = *(const float4*)&sep[t * 4];
}

// -------------------------------------------------- layernorm: X f32 -> Xn bf16
__global__ __launch_bounds__(256)
void k_ln(const float* __restrict__ X, bf16_t* __restrict__ Xn,
          const float* __restrict__ w, const float* __restrict__ bb,
          const int* __restrict__ cnt) {
    int b = blockIdx.y, n = blockIdx.x;
    int Nb = 1025 + cnt[b];
    if (n >= Nb) return;
    int t = threadIdx.x;
    const float* x = X + ((size_t)b * NMAX + n) * DIM;
    float4 v = *(const float4*)&x[t * 4];
    float s = v.x + v.y + v.z + v.w;
    float q = v.x * v.x + v.y * v.y + v.z * v.z + v.w * v.w;
    #pragma unroll
    for (int off = 32; off > 0; off >>= 1) {
        s += __shfl_xor(s, off);
        q += __shfl_xor(q, off);
    }
    __shared__ float ss[4], sq[4];
    int wave = t >> 6, lane = t & 63;
    if (lane == 0) { ss[wave] = s; sq[wave] = q; }
    __syncthreads();
    s = ss[0] + ss[1] + ss[2] + ss[3];
    q = sq[0] + sq[1] + sq[2] + sq[3];
    float mean = s * (1.0f / DIM);
    float var  = q * (1.0f / DIM) - mean * mean;
    float rstd = 1.0f / sqrtf(var + 1e-5f);
    float4 ww = *(const float4*)&w[t * 4];
    float4 b4 = *(const float4*)&bb[t * 4];
    ushort4 o;
    o.x = f2bf((v.x - mean) * rstd * ww.x + b4.x);
    o.y = f2bf((v.y - mean) * rstd * ww.y + b4.y);
    o.z = f2bf((v.z - mean) * rstd * ww.z + b4.z);
    o.w = f2bf((v.w - mean) * rstd * ww.w + b4.w);
    *(ushort4*)&(Xn + ((size_t)b * NMAX + n) * DIM)[t * 4] = o;
}

// ------------------------------------------------------- GEMM: A bf16, W f32
// C[b] (rows x Nout) = A[b] @ W + bias. EPI 0=store, 1=gelu+store, 2=residual add.
// OutT = float or bf16_t. Column tiles always cover full Nout (multiple of 128).
__device__ __forceinline__ void store4(float* p, float4 v)  { *(float4*)p = v; }
__device__ __forceinline__ void store4(bf16_t* p, float4 v) {
    ushort4 u; u.x = f2bf(v.x); u.y = f2bf(v.y); u.z = f2bf(v.z); u.w = f2bf(v.w);
    *(ushort4*)p = u;
}

template <int EPI, typename OutT>
__global__ __launch_bounds__(256)
void k_gemm(const bf16_t* __restrict__ A, size_t bsA, int ldA,
            const float* __restrict__ W, int ldW, const float* __restrict__ bias,
            OutT* __restrict__ Out, size_t bsO, int ldO,
            int K, const int* __restrict__ cnt, int bound_add, int rows_phys) {
    int b = blockIdx.z;
    int bound = cnt[b] + bound_add;
    int tr = blockIdx.y * 128;
    if (tr >= bound) return;
    int tc = blockIdx.x * 128;
    __shared__ float As[16][132];
    __shared__ float Bs[16][132];
    int tid = threadIdx.x;
    int tx = tid & 15, ty = tid >> 4;
    float acc[8][8] = {};
    const bf16_t* Ab = A + (size_t)b * bsA;
    for (int k0 = 0; k0 < K; k0 += 16) {
        #pragma unroll
        for (int p = 0; p < 2; ++p) {
            int rl = (tid >> 2) + p * 64;
            int kl = (tid & 3) * 4;
            int row = tr + rl;
            float4 f = make_float4(0.f, 0.f, 0.f, 0.f);
            if (row < rows_phys) {
                ushort4 u = *(const ushort4*)(Ab + (size_t)row * ldA + k0 + kl);
                f.x = bf2f(u.x); f.y = bf2f(u.y); f.z = bf2f(u.z); f.w = bf2f(u.w);
            }
            As[kl + 0][rl] = f.x; As[kl + 1][rl] = f.y;
            As[kl + 2][rl] = f.z; As[kl + 3][rl] = f.w;
        }
        #pragma unroll
        for (int p = 0; p < 2; ++p) {
            int kr = (tid >> 5) + p * 8;
            int cl = (tid & 31) * 4;
            *(float4*)&Bs[kr][cl] = *(const float4*)(W + (size_t)(k0 + kr) * ldW + tc + cl);
        }
        __syncthreads();
        #pragma unroll
        for (int k = 0; k < 16; ++k) {
            float a[8], bb[8];
            *(float4*)&a[0]  = *(const float4*)&As[k][ty * 8];
            *(float4*)&a[4]  = *(const float4*)&As[k][ty * 8 + 4];
            *(float4*)&bb[0] = *(const float4*)&Bs[k][tx * 8];
            *(float4*)&bb[4] = *(const float4*)&Bs[k][tx * 8 + 4];
            #pragma unroll
            for (int i = 0; i < 8; ++i)
                #pragma unroll
                for (int j = 0; j < 8; ++j)
                    acc[i][j] = fmaf(a[i], bb[j], acc[i][j]);
        }
        __syncthreads();
    }
    OutT* Ob = Out + (size_t)b * bsO;
    float4 bias0 = *(const float4*)&bias[tc + tx * 8];
    float4 bias1 = *(const float4*)&bias[tc + tx * 8 + 4];
    #pragma unroll
    for (int i = 0; i < 8; ++i) {
        int row = tr + ty * 8 + i;
        if (row >= rows_phys) continue;
        OutT* op = Ob + (size_t)row * ldO + tc + tx * 8;
        float4 v0, v1;
        v0.x = acc[i][0] + bias0.x; v0.y = acc[i][1] + bias0.y;
        v0.z = acc[i][2] + bias0.z; v0.w = acc[i][3] + bias0.w;
        v1.x = acc[i][4] + bias1.x; v1.y = acc[i][5] + bias1.y;
        v1.z = acc[i][6] + bias1.z; v1.w = acc[i][7] + bias1.w;
        if (EPI == 1) {
            v0.x = gelu_exact(v0.x); v0.y = gelu_exact(v0.y);
            v0.z = gelu_exact(v0.z); v0.w = gelu_exact(v0.w);
            v1.x = gelu_exact(v1.x); v1.y = gelu_exact(v1.y);
            v1.z = gelu_exact(v1.z); v1.w = gelu_exact(v1.w);
        }
        if (EPI == 2) {   // residual: OutT is float here
            float* fp = (float*)op;
            float4 o0 = *(float4*)fp, o1 = *(float4*)(fp + 4);
            v0.x += o0.x; v0.y += o0.y; v0.z += o0.z; v0.w += o0.w;
            v1.x += o1.x; v1.y += o1.y; v1.z += o1.z; v1.w += o1.w;
        }
        store4(op, v0);
        store4(op + 4, v1);
    }
}

// ------------------------------------------------- flash attention, bf16 QKV
// grid (ceil(NMAX/32), NHEAD, NBATCH); 4 waves/WG, wave owns 8 query rows,
// lane owns 4 consecutive dims. No running max (|s| small for this model).
__global__ __launch_bounds__(256)
void k_attn(const bf16_t* __restrict__ QKV, bf16_t* __restrict__ O,
            const int* __restrict__ cnt) {
    int b = blockIdx.z, h = blockIdx.y;
    int Nb = 1025 + cnt[b];
    int wave = threadIdx.x >> 6, lane = threadIdx.x & 63;
    int rowbase = blockIdx.x * 32 + wave * 8;
    if (rowbase >= Nb) return;
    const bf16_t* Qp = QKV + (size_t)b * NMAX * 3072;
    int doff = h * HD + lane * 4;
    float4 q[8], o[8];
    float l[8];
    const float sc = 0.0625f;   // HD^-0.5
    #pragma unroll
    for (int r = 0; r < 8; ++r) {
        int row = rowbase + r;
        float4 qv = make_float4(0.f, 0.f, 0.f, 0.f);
        if (row < Nb) {
            ushort4 u = *(const ushort4*)(Qp + (size_t)row * 3072 + doff);
            qv = make_float4(bf2f(u.x), bf2f(u.y), bf2f(u.z), bf2f(u.w));
        }
        q[r] = make_float4(qv.x * sc, qv.y * sc, qv.z * sc, qv.w * sc);
        o[r] = make_float4(0.f, 0.f, 0.f, 0.f);
        l[r] = 0.f;
    }
    const bf16_t* Kp = Qp + 1024 + doff;
    const bf16_t* Vp = Qp + 2048 + doff;
    for (int m = 0; m < Nb; ++m) {
        ushort4 uk = *(const ushort4*)(Kp + (size_t)m * 3072);
        float4 kv = make_float4(bf2f(uk.x), bf2f(uk.y), bf2f(uk.z), bf2f(uk.w));
        float s[8];
        #pragma unroll
        for (int r = 0; r < 8; ++r)
            s[r] = q[r].x * kv.x + q[r].y * kv.y + q[r].z * kv.z + q[r].w * kv.w;
        #pragma unroll
        for (int off = 32; off > 0; off >>= 1)
            #pragma unroll
            for (int r = 0; r < 8; ++r)
                s[r] += __shfl_xor(s[r], off);
        ushort4 uv = *(const ushort4*)(Vp + (size_t)m * 3072);
        float4 vv = make_float4(bf2f(uv.x), bf2f(uv.y), bf2f(uv.z), bf2f(uv.w));
        #pragma unroll
        for (int r = 0; r < 8; ++r) {
            float p = __expf(s[r]);
            l[r] += p;
            o[r].x = fmaf(p, vv.x, o[r].x);
            o[r].y = fmaf(p, vv.y, o[r].y);
            o[r].z = fmaf(p, vv.z, o[r].z);
            o[r].w = fmaf(p, vv.w, o[r].w);
        }
    }
    #pragma unroll
    for (int r = 0; r < 8; ++r) {
        int row = rowbase + r;
        if (row < Nb) {
            float inv = 1.0f / l[r];
            ushort4 res;
            res.x = f2bf(o[r].x * inv); res.y = f2bf(o[r].y * inv);
            res.z = f2bf(o[r].z * inv); res.w = f2bf(o[r].w * inv);
            *(ushort4*)(O + ((size_t)b * NMAX + row) * DIM + doff) = res;
        }
    }
}

// ---------------------------------------------------------------- output
__global__ __launch_bounds__(256)
void k_out(const float* __restrict__ X, const float* __restrict__ emb,
           const int* __restrict__ cnt, float* __restrict__ out) {
    int b = blockIdx.y, n = blockIdx.x, t = threadIdx.x;
    const float* s = (cnt[b] > 0) ? X + ((size_t)b * NMAX + n) * DIM
                                  : emb + ((size_t)b * NQ + n) * DIM;
    *(float4*)&out[((size_t)b * NQ + n) * DIM + t * 4] = *(const float4*)&s[t * 4];
}

// ============================================================== launch
extern "C" void kernel_launch(void* const* d_in, const int* in_sizes, int n_in,
                              void* d_out, int out_size, void* d_ws, size_t ws_size,
                              hipStream_t stream) {
    const float* emb    = (const float*)d_in[0];
    const float* depth  = (const float*)d_in[1];
    const int*   mask   = (const int*)d_in[2];
    const float* gauss  = (const float*)d_in[5];
    const float* d2f_w1 = (const float*)d_in[6];
    const float* d2f_b1 = (const float*)d_in[7];
    const float* d2f_w2 = (const float*)d_in[8];
    const float* d2f_b2 = (const float*)d_in[9];
    const float* sep    = (const float*)d_in[10];
    const float* ln1_w  = (const float*)d_in[11];
    const float* ln1_b  = (const float*)d_in[12];
    const float* qkv_w  = (const float*)d_in[13];
    const float* qkv_b  = (const float*)d_in[14];
    const float* proj_w = (const float*)d_in[15];
    const float* proj_b = (const float*)d_in[16];
    const float* ln2_w  = (const float*)d_in[17];
    const float* ln2_b  = (const float*)d_in[18];
    const float* mlp_w1 = (const float*)d_in[19];
    const float* mlp_b1 = (const float*)d_in[20];
    const float* mlp_w2 = (const float*)d_in[21];
    const float* mlp_b2 = (const float*)d_in[22];
    float* out = (float*)d_out;

    // ---- workspace layout (bytes), total 163,668,224 ≈ 156 MiB ----
    // [cnt 256][pidx 36864 -> 37120][zero_bias 4096 -> 41216]
    // [X f32 54,542,336 -> 54,583,552][Xn bf16 27,271,168 -> 81,854,720]
    // [region bf16 81,813,504 -> 163,668,224]  (Hp / QKV / MLP-hidden union)
    char* wsb = (char*)d_ws;
    int*    cnt   = (int*)wsb;
    int*    pidx  = (int*)(wsb + 256);
    float*  zbias = (float*)(wsb + 37120);
    float*  X     = (float*)(wsb + 41216);
    bf16_t* Xn    = (bf16_t*)(wsb + 41216 + (size_t)NBATCH * NMAX * DIM * 4);
    bf16_t* Qb    = (bf16_t*)(wsb + 41216 + (size_t)NBATCH * NMAX * DIM * 6);
    if (ws_size < (size_t)163668224) return;   // clean fail (absmax=stub) instead of OOB crash

    k_compact<<<NBATCH, 256, 0, stream>>>(mask, cnt, pidx);
    k_zerobias<<<4, 256, 0, stream>>>(zbias);
    k_init_query<<<dim3(NQ, NBATCH), 256, 0, stream>>>(emb, gauss, X);
    k_prompt_h<<<dim3(MASKN, NBATCH), 256, 0, stream>>>(depth, d2f_w1, d2f_b1, cnt, pidx, Qb);
    // prompt features: Hp (2304x512 bf16) @ w2 (512x1024 f32) + b2 -> X rows 1025..
    k_gemm<0, float><<<dim3(8, 18, NBATCH), 256, 0, stream>>>(
        Qb, (size_t)MASKN * 512, 512, d2f_w2, DIM, d2f_b2,
        X + (size_t)1025 * DIM, (size_t)NMAX * DIM, DIM, 512, cnt, 0, MASKN);
    k_pe_prompt<<<dim3(MASKN, NBATCH), 256, 0, stream>>>(gauss, cnt, pidx, X);

    for (int i = 0; i < 2; ++i) {
        k_sep<<<NBATCH, 256, 0, stream>>>(X, sep + (size_t)i * DIM);
        k_ln<<<dim3(NMAX, NBATCH), 256, 0, stream>>>(X, Xn, ln1_w + i * DIM, ln1_b + i * DIM, cnt);
        // QKV: Xn (N x 1024) @ qkv_w (1024 x 3072) -> Qb bf16
        k_gemm<0, bf16_t><<<dim3(24, 27, NBATCH), 256, 0, stream>>>(
            Xn, (size_t)NMAX * DIM, DIM,
            qkv_w + (size_t)i * DIM * 3072, 3072, qkv_b + (size_t)i * 3072,
            Qb, (size_t)NMAX * 3072, 3072, DIM, cnt, 1025, NMAX);
        // attention: QKV -> O (overwrites Xn, dead after QKV GEMM)
        k_attn<<<dim3(105, NHEAD, NBATCH), 256, 0, stream>>>(Qb, Xn, cnt);
        // proj: O @ proj_w, residual into X (f32)
        k_gemm<2, float><<<dim3(8, 27, NBATCH), 256, 0, stream>>>(
            Xn, (size_t)NMAX * DIM, DIM,
            proj_w + (size_t)i * DIM * DIM, DIM, proj_b + (size_t)i * DIM,
            X, (size_t)NMAX * DIM, DIM, DIM, cnt, 1025, NMAX);
        k_ln<<<dim3(NMAX, NBATCH), 256, 0, stream>>>(X, Xn, ln2_w + i * DIM, ln2_b + i * DIM, cnt);
        // MLP in two hidden chunks of 2048 (H reuses Qb region, QKV dead)
        for (int c = 0; c < 2; ++c) {
            k_gemm<1, bf16_t><<<dim3(16, 27, NBATCH), 256, 0, stream>>>(
                Xn, (size_t)NMAX * DIM, DIM,
                mlp_w1 + (size_t)i * DIM * 4096 + c * 2048, 4096,
                mlp_b1 + (size_t)i * 4096 + c * 2048,
                Qb, (size_t)NMAX * 2048, 2048, DIM, cnt, 1025, NMAX);
            k_gemm<2, float><<<dim3(8, 27, NBATCH), 256, 0, stream>>>(
                Qb, (size_t)NMAX * 2048, 2048,
                mlp_w2 + (size_t)i * 4096 * DIM + (size_t)c * 2048 * DIM, DIM,
                (c == 0) ? (mlp_b2 + (size_t)i * DIM) : zbias,
                X, (size_t)NMAX * DIM, DIM, 2048, cnt, 1025, NMAX);
        }
    }

    k_out<<<dim3(NQ, NBATCH), 256, 0, stream>>>(X, emb, cnt, out);
    (void)in_sizes; (void)n_in; (void)out_size;
}

// Round 3
// 7042.332 us; speedup vs baseline: 3.2730x; 3.2730x over previous
//
#include <hip/hip_runtime.h>
#include <math.h>

#define NBATCH 4
#define DIM    1024
#define NHEAD  4
#define HD     256
#define NQ     1024
#define MASKN  2304           // 48*48
#define NMAX   3329           // 1024 query + 1 sep + 2304 max prompts
#define TWO_PI 6.283185307179586f

typedef unsigned short bf16_t;
typedef short bf16x8 __attribute__((ext_vector_type(8)));
typedef float f32x4  __attribute__((ext_vector_type(4)));

__device__ __forceinline__ float gelu_exact(float x) {
    return 0.5f * x * (1.0f + erff(x * 0.70710678118654752f));
}
__device__ __forceinline__ float bf2f(bf16_t h) {
    return __uint_as_float((unsigned)h << 16);
}
__device__ __forceinline__ bf16_t f2bf(float f) {   // round-to-nearest-even
    unsigned u = __float_as_uint(f);
    return (bf16_t)((u + 0x7FFFu + ((u >> 16) & 1u)) >> 16);
}

// ---------------------------------------------------------------- compaction
__global__ __launch_bounds__(256)
void k_compact(const int* __restrict__ mask, int* __restrict__ cnt, int* __restrict__ pidx) {
    int b = blockIdx.x;
    __shared__ int sc;
    if (threadIdx.x == 0) sc = 0;
    __syncthreads();
    for (int c = threadIdx.x; c < MASKN; c += blockDim.x)
        if (mask[b * MASKN + c] > 0) {
            int p = atomicAdd(&sc, 1);
            pidx[b * MASKN + p] = c;
        }
    __syncthreads();
    if (threadIdx.x == 0) cnt[b] = sc;
}

__global__ __launch_bounds__(256)
void k_zerobias(float* __restrict__ z) {
    z[blockIdx.x * 256 + threadIdx.x] = 0.f;
}

// ------------------------------------------------- query tokens: emb + PE (f32 X)
__global__ __launch_bounds__(256)
void k_init_query(const float* __restrict__ emb, const float* __restrict__ gauss,
                  float* __restrict__ X) {
    int b = blockIdx.y, n = blockIdx.x, t = threadIdx.x;
    float fx = 2.0f * (((n & 31) + 0.5f) / 32.0f) - 1.0f;
    float fy = 2.0f * (((n >> 5) + 0.5f) / 32.0f) - 1.0f;
    const float* e = emb + ((size_t)b * NQ + n) * DIM;
    float* x = X + ((size_t)b * NMAX + n) * DIM;
    for (int d = t; d < 512; d += 256) {
        float ang = TWO_PI * (fx * gauss[d] + fy * gauss[512 + d]);
        float sn, cs; sincosf(ang, &sn, &cs);
        x[d]       = e[d] + sn;
        x[d + 512] = e[d + 512] + cs;
    }
}

// --------------------------------- prompt hidden: gelu(d*w1+b1) (M x 512) bf16
__global__ __launch_bounds__(256)
void k_prompt_h(const float* __restrict__ depth, const float* __restrict__ w1,
                const float* __restrict__ b1, const int* __restrict__ cnt,
                const int* __restrict__ pidx, bf16_t* __restrict__ Hp) {
    int b = blockIdx.y, s = blockIdx.x, t = threadIdx.x;
    bf16_t* hp = Hp + ((size_t)b * MASKN + s) * 512;
    if (s >= cnt[b]) { hp[t] = 0; hp[t + 256] = 0; return; }
    int cell = pidx[b * MASKN + s];
    float d = depth[b * MASKN + cell];
    for (int j = t; j < 512; j += 256)
        hp[j] = f2bf(gelu_exact(fmaf(d, w1[j], b1[j])));
}

// ------------------------------------------ add prompt PE into X rows (f32)
__global__ __launch_bounds__(256)
void k_pe_prompt(const float* __restrict__ gauss, const int* __restrict__ cnt,
                 const int* __restrict__ pidx, float* __restrict__ X) {
    int b = blockIdx.y, s = blockIdx.x, t = threadIdx.x;
    if (s >= cnt[b]) return;
    int cell = pidx[b * MASKN + s];
    int r = cell / 48, c = cell % 48;
    float fx = 2.0f * ((c + 0.5f) / 48.0f) - 1.0f;
    float fy = 2.0f * ((r + 0.5f) / 48.0f) - 1.0f;
    float* x = X + ((size_t)b * NMAX + 1025 + s) * DIM;
    for (int d = t; d < 512; d += 256) {
        float ang = TWO_PI * (fx * gauss[d] + fy * gauss[512 + d]);
        float sn, cs; sincosf(ang, &sn, &cs);
        x[d]       += sn;
        x[d + 512] += cs;
    }
}

// ---------------------------------------------------------------- sep token
__global__ __launch_bounds__(256)
void k_sep(float* __restrict__ X, const float* __restrict__ sep) {
    int b = blockIdx.x, t = threadIdx.x;
    float* x = X + ((size_t)b * NMAX + 1024) * DIM;
    *(float4*)&x[t * 4] = *(const float4*)&sep[t * 4];
}

// -------------------------------------------------- layernorm: X f32 -> Xn bf16
__global__ __launch_bounds__(256)
void k_ln(const float* __restrict__ X, bf16_t* __restrict__ Xn,
          const float* __restrict__ w, const float* __restrict__ bb,
          const int* __restrict__ cnt) {
    int b = blockIdx.y, n = blockIdx.x;
    int Nb = 1025 + cnt[b];
    if (n >= Nb) return;
    int t = threadIdx.x;
    const float* x = X + ((size_t)b * NMAX + n) * DIM;
    float4 v = *(const float4*)&x[t * 4];
    float s = v.x + v.y + v.z + v.w;
    float q = v.x * v.x + v.y * v.y + v.z * v.z + v.w * v.w;
    #pragma unroll
    for (int off = 32; off > 0; off >>= 1) {
        s += __shfl_xor(s, off);
        q += __shfl_xor(q, off);
    }
    __shared__ float ss[4], sq[4];
    int wave = t >> 6, lane = t & 63;
    if (lane == 0) { ss[wave] = s; sq[wave] = q; }
    __syncthreads();
    s = ss[0] + ss[1] + ss[2] + ss[3];
    q = sq[0] + sq[1] + sq[2] + sq[3];
    float mean = s * (1.0f / DIM);
    float var  = q * (1.0f / DIM) - mean * mean;
    float rstd = 1.0f / sqrtf(var + 1e-5f);
    float4 ww = *(const float4*)&w[t * 4];
    float4 b4 = *(const float4*)&bb[t * 4];
    ushort4 o;
    o.x = f2bf((v.x - mean) * rstd * ww.x + b4.x);
    o.y = f2bf((v.y - mean) * rstd * ww.y + b4.y);
    o.z = f2bf((v.z - mean) * rstd * ww.z + b4.z);
    o.w = f2bf((v.w - mean) * rstd * ww.w + b4.w);
    *(ushort4*)&(Xn + ((size_t)b * NMAX + n) * DIM)[t * 4] = o;
}

// ------------------------------------------------------- GEMM: A bf16, W f32
__device__ __forceinline__ void store4(float* p, float4 v)  { *(float4*)p = v; }
__device__ __forceinline__ void store4(bf16_t* p, float4 v) {
    ushort4 u; u.x = f2bf(v.x); u.y = f2bf(v.y); u.z = f2bf(v.z); u.w = f2bf(v.w);
    *(ushort4*)p = u;
}

template <int EPI, typename OutT>
__global__ __launch_bounds__(256)
void k_gemm(const bf16_t* __restrict__ A, size_t bsA, int ldA,
            const float* __restrict__ W, int ldW, const float* __restrict__ bias,
            OutT* __restrict__ Out, size_t bsO, int ldO,
            int K, const int* __restrict__ cnt, int bound_add, int rows_phys) {
    int b = blockIdx.z;
    int bound = cnt[b] + bound_add;
    int tr = blockIdx.y * 128;
    if (tr >= bound) return;
    int tc = blockIdx.x * 128;
    __shared__ float As[16][132];
    __shared__ float Bs[16][132];
    int tid = threadIdx.x;
    int tx = tid & 15, ty = tid >> 4;
    float acc[8][8] = {};
    const bf16_t* Ab = A + (size_t)b * bsA;
    for (int k0 = 0; k0 < K; k0 += 16) {
        #pragma unroll
        for (int p = 0; p < 2; ++p) {
            int rl = (tid >> 2) + p * 64;
            int kl = (tid & 3) * 4;
            int row = tr + rl;
            float4 f = make_float4(0.f, 0.f, 0.f, 0.f);
            if (row < rows_phys) {
                ushort4 u = *(const ushort4*)(Ab + (size_t)row * ldA + k0 + kl);
                f.x = bf2f(u.x); f.y = bf2f(u.y); f.z = bf2f(u.z); f.w = bf2f(u.w);
            }
            As[kl + 0][rl] = f.x; As[kl + 1][rl] = f.y;
            As[kl + 2][rl] = f.z; As[kl + 3][rl] = f.w;
        }
        #pragma unroll
        for (int p = 0; p < 2; ++p) {
            int kr = (tid >> 5) + p * 8;
            int cl = (tid & 31) * 4;
            *(float4*)&Bs[kr][cl] = *(const float4*)(W + (size_t)(k0 + kr) * ldW + tc + cl);
        }
        __syncthreads();
        #pragma unroll
        for (int k = 0; k < 16; ++k) {
            float a[8], bb[8];
            *(float4*)&a[0]  = *(const float4*)&As[k][ty * 8];
            *(float4*)&a[4]  = *(const float4*)&As[k][ty * 8 + 4];
            *(float4*)&bb[0] = *(const float4*)&Bs[k][tx * 8];
            *(float4*)&bb[4] = *(const float4*)&Bs[k][tx * 8 + 4];
            #pragma unroll
            for (int i = 0; i < 8; ++i)
                #pragma unroll
                for (int j = 0; j < 8; ++j)
                    acc[i][j] = fmaf(a[i], bb[j], acc[i][j]);
        }
        __syncthreads();
    }
    OutT* Ob = Out + (size_t)b * bsO;
    float4 bias0 = *(const float4*)&bias[tc + tx * 8];
    float4 bias1 = *(const float4*)&bias[tc + tx * 8 + 4];
    #pragma unroll
    for (int i = 0; i < 8; ++i) {
        int row = tr + ty * 8 + i;
        if (row >= rows_phys) continue;
        OutT* op = Ob + (size_t)row * ldO + tc + tx * 8;
        float4 v0, v1;
        v0.x = acc[i][0] + bias0.x; v0.y = acc[i][1] + bias0.y;
        v0.z = acc[i][2] + bias0.z; v0.w = acc[i][3] + bias0.w;
        v1.x = acc[i][4] + bias1.x; v1.y = acc[i][5] + bias1.y;
        v1.z = acc[i][6] + bias1.z; v1.w = acc[i][7] + bias1.w;
        if (EPI == 1) {
            v0.x = gelu_exact(v0.x); v0.y = gelu_exact(v0.y);
            v0.z = gelu_exact(v0.z); v0.w = gelu_exact(v0.w);
            v1.x = gelu_exact(v1.x); v1.y = gelu_exact(v1.y);
            v1.z = gelu_exact(v1.z); v1.w = gelu_exact(v1.w);
        }
        if (EPI == 2) {
            float* fp = (float*)op;
            float4 o0 = *(float4*)fp, o1 = *(float4*)(fp + 4);
            v0.x += o0.x; v0.y += o0.y; v0.z += o0.z; v0.w += o0.w;
            v1.x += o1.x; v1.y += o1.y; v1.z += o1.z; v1.w += o1.w;
        }
        store4(op, v0);
        store4(op + 4, v1);
    }
}

// =================================================== MFMA flash attention
// One WG per (64 query rows, head, batch). 4 waves x 16 rows.
// mfma_f32_16x16x32_bf16; A[m=lane&15][k=quad*8+j]; C/D col=lane&15,row=quad*4+reg.
// K-tile (32 keys) row-major in LDS (+8 pad); V-tile transposed (Vt[dim][key],
// stride 40 -> 16B-aligned b128, conflict-spread). P round-trips LDS (C->A).
__global__ __launch_bounds__(256)
void k_attn_mfma(const bf16_t* __restrict__ QKV, bf16_t* __restrict__ O,
                 const int* __restrict__ cnt) {
    int b = blockIdx.z, h = blockIdx.y;
    int Nb = 1025 + cnt[b];
    int qbase = blockIdx.x * 64;
    if (qbase >= Nb) return;

    __shared__ bf16_t Kt[32][264];      // 16.9 KB
    __shared__ bf16_t Vt[256][40];      // 20.5 KB
    __shared__ bf16_t Pt[4][16][40];    // 5.1 KB per-wave P

    int tid  = threadIdx.x;
    int wave = tid >> 6, lane = tid & 63;
    int quad = lane >> 4, l16 = lane & 15;

    // Q fragments (A-layout): 8 k-chunks of 32 dims
    int qrow  = qbase + wave * 16 + l16;
    int qrowc = qrow < NMAX ? qrow : NMAX - 1;
    const bf16_t* Qp = QKV + (size_t)b * NMAX * 3072 + (size_t)qrowc * 3072 + h * HD;
    bf16x8 qf[8];
    #pragma unroll
    for (int c = 0; c < 8; ++c)
        qf[c] = *(const bf16x8*)(Qp + c * 32 + quad * 8);

    f32x4 Oacc[16];
    #pragma unroll
    for (int n = 0; n < 16; ++n) Oacc[n] = (f32x4){0.f, 0.f, 0.f, 0.f};
    float l[4] = {0.f, 0.f, 0.f, 0.f};

    const bf16_t* Kg = QKV + (size_t)b * NMAX * 3072 + 1024 + h * HD;
    const bf16_t* Vg = QKV + (size_t)b * NMAX * 3072 + 2048 + h * HD;

    int krow_s = tid >> 3;          // K stage: row 0..31, dims (tid&7)*8 + i*64
    int kd_s   = (tid & 7) * 8;
    int vd_s   = (tid >> 3) * 8;    // V stage: 8 dims, 4 rows per thread
    int vr_s   = (tid & 7) * 4;

    for (int kt = 0; kt < Nb; kt += 32) {
        __syncthreads();            // previous tile fully consumed
        #pragma unroll
        for (int i = 0; i < 4; ++i) {
            int gk = kt + krow_s;
            int d  = kd_s + i * 64;
            bf16x8 v = (bf16x8){0,0,0,0,0,0,0,0};
            if (gk < Nb) v = *(const bf16x8*)(Kg + (size_t)gk * 3072 + d);
            *(bf16x8*)&Kt[krow_s][d] = v;
        }
        {
            bf16x8 vv[4];
            #pragma unroll
            for (int r = 0; r < 4; ++r) {
                int gk = kt + vr_s + r;
                vv[r] = (bf16x8){0,0,0,0,0,0,0,0};
                if (gk < Nb) vv[r] = *(const bf16x8*)(Vg + (size_t)gk * 3072 + vd_s);
            }
            #pragma unroll
            for (int j = 0; j < 8; ++j) {
                ushort4 pk;
                pk.x = (unsigned short)vv[0][j];
                pk.y = (unsigned short)vv[1][j];
                pk.z = (unsigned short)vv[2][j];
                pk.w = (unsigned short)vv[3][j];
                *(ushort4*)&Vt[vd_s + j][vr_s] = pk;
            }
        }
        __syncthreads();

        // S = Q·K^T : two 16-key column blocks
        f32x4 c0 = (f32x4){0.f,0.f,0.f,0.f}, c1 = (f32x4){0.f,0.f,0.f,0.f};
        #pragma unroll
        for (int c = 0; c < 8; ++c) {
            bf16x8 kb0 = *(const bf16x8*)&Kt[l16     ][c * 32 + quad * 8];
            bf16x8 kb1 = *(const bf16x8*)&Kt[l16 + 16][c * 32 + quad * 8];
            c0 = __builtin_amdgcn_mfma_f32_16x16x32_bf16(qf[c], kb0, c0, 0, 0, 0);
            c1 = __builtin_amdgcn_mfma_f32_16x16x32_bf16(qf[c], kb1, c1, 0, 0, 0);
        }
        // softmax numerator (no max-sub: scores small, validated R2)
        float ls[4];
        #pragma unroll
        for (int r = 0; r < 4; ++r) {
            float p0 = (kt + l16      < Nb) ? __expf(c0[r] * 0.0625f) : 0.f;
            float p1 = (kt + 16 + l16 < Nb) ? __expf(c1[r] * 0.0625f) : 0.f;
            Pt[wave][quad * 4 + r][l16]      = f2bf(p0);
            Pt[wave][quad * 4 + r][l16 + 16] = f2bf(p1);
            ls[r] = p0 + p1;
        }
        #pragma unroll
        for (int off = 1; off < 16; off <<= 1)
            #pragma unroll
            for (int r = 0; r < 4; ++r)
                ls[r] += __shfl_xor(ls[r], off);
        #pragma unroll
        for (int r = 0; r < 4; ++r) l[r] += ls[r];

        // P·V : P A-frag from per-wave LDS, V B-frags from transposed tile
        bf16x8 pa = *(const bf16x8*)&Pt[wave][l16][quad * 8];
        #pragma unroll
        for (int n = 0; n < 16; ++n) {
            bf16x8 vb = *(const bf16x8*)&Vt[n * 16 + l16][quad * 8];
            Oacc[n] = __builtin_amdgcn_mfma_f32_16x16x32_bf16(pa, vb, Oacc[n], 0, 0, 0);
        }
    }

    float inv[4];
    #pragma unroll
    for (int r = 0; r < 4; ++r) inv[r] = 1.0f / l[r];
    bf16_t* Op = O + (size_t)b * NMAX * DIM + h * HD;
    #pragma unroll
    for (int r = 0; r < 4; ++r) {
        int row = qbase + wave * 16 + quad * 4 + r;
        if (row < Nb) {
            bf16_t* op = Op + (size_t)row * DIM;
            #pragma unroll
            for (int n = 0; n < 16; ++n)
                op[n * 16 + l16] = f2bf(Oacc[n][r] * inv[r]);
        }
    }
}

// ---------------------------------------------------------------- output
__global__ __launch_bounds__(256)
void k_out(const float* __restrict__ X, const float* __restrict__ emb,
           const int* __restrict__ cnt, float* __restrict__ out) {
    int b = blockIdx.y, n = blockIdx.x, t = threadIdx.x;
    const float* s = (cnt[b] > 0) ? X + ((size_t)b * NMAX + n) * DIM
                                  : emb + ((size_t)b * NQ + n) * DIM;
    *(float4*)&out[((size_t)b * NQ + n) * DIM + t * 4] = *(const float4*)&s[t * 4];
}

// ============================================================== launch
extern "C" void kernel_launch(void* const* d_in, const int* in_sizes, int n_in,
                              void* d_out, int out_size, void* d_ws, size_t ws_size,
                              hipStream_t stream) {
    const float* emb    = (const float*)d_in[0];
    const float* depth  = (const float*)d_in[1];
    const int*   mask   = (const int*)d_in[2];
    const float* gauss  = (const float*)d_in[5];
    const float* d2f_w1 = (const float*)d_in[6];
    const float* d2f_b1 = (const float*)d_in[7];
    const float* d2f_w2 = (const float*)d_in[8];
    const float* d2f_b2 = (const float*)d_in[9];
    const float* sep    = (const float*)d_in[10];
    const float* ln1_w  = (const float*)d_in[11];
    const float* ln1_b  = (const float*)d_in[12];
    const float* qkv_w  = (const float*)d_in[13];
    const float* qkv_b  = (const float*)d_in[14];
    const float* proj_w = (const float*)d_in[15];
    const float* proj_b = (const float*)d_in[16];
    const float* ln2_w  = (const float*)d_in[17];
    const float* ln2_b  = (const float*)d_in[18];
    const float* mlp_w1 = (const float*)d_in[19];
    const float* mlp_b1 = (const float*)d_in[20];
    const float* mlp_w2 = (const float*)d_in[21];
    const float* mlp_b2 = (const float*)d_in[22];
    float* out = (float*)d_out;

    char* wsb = (char*)d_ws;
    int*    cnt   = (int*)wsb;
    int*    pidx  = (int*)(wsb + 256);
    float*  zbias = (float*)(wsb + 37120);
    float*  X     = (float*)(wsb + 41216);
    bf16_t* Xn    = (bf16_t*)(wsb + 41216 + (size_t)NBATCH * NMAX * DIM * 4);
    bf16_t* Qb    = (bf16_t*)(wsb + 41216 + (size_t)NBATCH * NMAX * DIM * 6);
    if (ws_size < (size_t)163668224) return;

    k_compact<<<NBATCH, 256, 0, stream>>>(mask, cnt, pidx);
    k_zerobias<<<4, 256, 0, stream>>>(zbias);
    k_init_query<<<dim3(NQ, NBATCH), 256, 0, stream>>>(emb, gauss, X);
    k_prompt_h<<<dim3(MASKN, NBATCH), 256, 0, stream>>>(depth, d2f_w1, d2f_b1, cnt, pidx, Qb);
    k_gemm<0, float><<<dim3(8, 18, NBATCH), 256, 0, stream>>>(
        Qb, (size_t)MASKN * 512, 512, d2f_w2, DIM, d2f_b2,
        X + (size_t)1025 * DIM, (size_t)NMAX * DIM, DIM, 512, cnt, 0, MASKN);
    k_pe_prompt<<<dim3(MASKN, NBATCH), 256, 0, stream>>>(gauss, cnt, pidx, X);

    for (int i = 0; i < 2; ++i) {
        k_sep<<<NBATCH, 256, 0, stream>>>(X, sep + (size_t)i * DIM);
        k_ln<<<dim3(NMAX, NBATCH), 256, 0, stream>>>(X, Xn, ln1_w + i * DIM, ln1_b + i * DIM, cnt);
        k_gemm<0, bf16_t><<<dim3(24, 27, NBATCH), 256, 0, stream>>>(
            Xn, (size_t)NMAX * DIM, DIM,
            qkv_w + (size_t)i * DIM * 3072, 3072, qkv_b + (size_t)i * 3072,
            Qb, (size_t)NMAX * 3072, 3072, DIM, cnt, 1025, NMAX);
        k_attn_mfma<<<dim3(53, NHEAD, NBATCH), 256, 0, stream>>>(Qb, Xn, cnt);
        k_gemm<2, float><<<dim3(8, 27, NBATCH), 256, 0, stream>>>(
            Xn, (size_t)NMAX * DIM, DIM,
            proj_w + (size_t)i * DIM * DIM, DIM, proj_b + (size_t)i * DIM,
            X, (size_t)NMAX * DIM, DIM, DIM, cnt, 1025, NMAX);
        k_ln<<<dim3(NMAX, NBATCH), 256, 0, stream>>>(X, Xn, ln2_w + i * DIM, ln2_b + i * DIM, cnt);
        for (int c = 0; c < 2; ++c) {
            k_gemm<1, bf16_t><<<dim3(16, 27, NBATCH), 256, 0, stream>>>(
                Xn, (size_t)NMAX * DIM, DIM,
                mlp_w1 + (size_t)i * DIM * 4096 + c * 2048, 4096,
                mlp_b1 + (size_t)i * 4096 + c * 2048,
                Qb, (size_t)NMAX * 2048, 2048, DIM, cnt, 1025, NMAX);
            k_gemm<2, float><<<dim3(8, 27, NBATCH), 256, 0, stream>>>(
                Qb, (size_t)NMAX * 2048, 2048,
                mlp_w2 + (size_t)i * 4096 * DIM + (size_t)c * 2048 * DIM, DIM,
                (c == 0) ? (mlp_b2 + (size_t)i * DIM) : zbias,
                X, (size_t)NMAX * DIM, DIM, 2048, cnt, 1025, NMAX);
        }
    }

    k_out<<<dim3(NQ, NBATCH), 256, 0, stream>>>(X, emb, cnt, out);
    (void)in_sizes; (void)n_in; (void)out_size;
}

// Round 4
// 1980.482 us; speedup vs baseline: 11.6384x; 3.5559x over previous
//
#include <hip/hip_runtime.h>
#include <math.h>

#define NBATCH 4
#define DIM    1024
#define NHEAD  4
#define HD     256
#define NQ     1024
#define MASKN  2304           // 48*48
#define NMAX   3329           // 1024 query + 1 sep + 2304 max prompts
#define TWO_PI 6.283185307179586f

typedef unsigned short bf16_t;
typedef short bf16x8 __attribute__((ext_vector_type(8)));
typedef float f32x4  __attribute__((ext_vector_type(4)));

__device__ __forceinline__ float gelu_exact(float x) {
    return 0.5f * x * (1.0f + erff(x * 0.70710678118654752f));
}
__device__ __forceinline__ float bf2f(bf16_t h) {
    return __uint_as_float((unsigned)h << 16);
}
__device__ __forceinline__ bf16_t f2bf(float f) {   // round-to-nearest-even
    unsigned u = __float_as_uint(f);
    return (bf16_t)((u + 0x7FFFu + ((u >> 16) & 1u)) >> 16);
}

// ---------------------------------------------------------------- compaction
__global__ __launch_bounds__(256)
void k_compact(const int* __restrict__ mask, int* __restrict__ cnt, int* __restrict__ pidx) {
    int b = blockIdx.x;
    __shared__ int sc;
    if (threadIdx.x == 0) sc = 0;
    __syncthreads();
    for (int c = threadIdx.x; c < MASKN; c += blockDim.x)
        if (mask[b * MASKN + c] > 0) {
            int p = atomicAdd(&sc, 1);
            pidx[b * MASKN + p] = c;
        }
    __syncthreads();
    if (threadIdx.x == 0) cnt[b] = sc;
}

__global__ __launch_bounds__(256)
void k_zerobias(float* __restrict__ z) {
    z[blockIdx.x * 256 + threadIdx.x] = 0.f;
}

// ------------------------------------------------- query tokens: emb + PE (f32 X)
__global__ __launch_bounds__(256)
void k_init_query(const float* __restrict__ emb, const float* __restrict__ gauss,
                  float* __restrict__ X) {
    int b = blockIdx.y, n = blockIdx.x, t = threadIdx.x;
    float fx = 2.0f * (((n & 31) + 0.5f) / 32.0f) - 1.0f;
    float fy = 2.0f * (((n >> 5) + 0.5f) / 32.0f) - 1.0f;
    const float* e = emb + ((size_t)b * NQ + n) * DIM;
    float* x = X + ((size_t)b * NMAX + n) * DIM;
    for (int d = t; d < 512; d += 256) {
        float ang = TWO_PI * (fx * gauss[d] + fy * gauss[512 + d]);
        float sn, cs; sincosf(ang, &sn, &cs);
        x[d]       = e[d] + sn;
        x[d + 512] = e[d + 512] + cs;
    }
}

// --------------------------------- prompt hidden: gelu(d*w1+b1) (M x 512) bf16
__global__ __launch_bounds__(256)
void k_prompt_h(const float* __restrict__ depth, const float* __restrict__ w1,
                const float* __restrict__ b1, const int* __restrict__ cnt,
                const int* __restrict__ pidx, bf16_t* __restrict__ Hp) {
    int b = blockIdx.y, s = blockIdx.x, t = threadIdx.x;
    bf16_t* hp = Hp + ((size_t)b * MASKN + s) * 512;
    if (s >= cnt[b]) { hp[t] = 0; hp[t + 256] = 0; return; }
    int cell = pidx[b * MASKN + s];
    float d = depth[b * MASKN + cell];
    for (int j = t; j < 512; j += 256)
        hp[j] = f2bf(gelu_exact(fmaf(d, w1[j], b1[j])));
}

// ------------------------------------------ add prompt PE into X rows (f32)
__global__ __launch_bounds__(256)
void k_pe_prompt(const float* __restrict__ gauss, const int* __restrict__ cnt,
                 const int* __restrict__ pidx, float* __restrict__ X) {
    int b = blockIdx.y, s = blockIdx.x, t = threadIdx.x;
    if (s >= cnt[b]) return;
    int cell = pidx[b * MASKN + s];
    int r = cell / 48, c = cell % 48;
    float fx = 2.0f * ((c + 0.5f) / 48.0f) - 1.0f;
    float fy = 2.0f * ((r + 0.5f) / 48.0f) - 1.0f;
    float* x = X + ((size_t)b * NMAX + 1025 + s) * DIM;
    for (int d = t; d < 512; d += 256) {
        float ang = TWO_PI * (fx * gauss[d] + fy * gauss[512 + d]);
        float sn, cs; sincosf(ang, &sn, &cs);
        x[d]       += sn;
        x[d + 512] += cs;
    }
}

// ---------------------------------------------------------------- sep token
__global__ __launch_bounds__(256)
void k_sep(float* __restrict__ X, const float* __restrict__ sep) {
    int b = blockIdx.x, t = threadIdx.x;
    float* x = X + ((size_t)b * NMAX + 1024) * DIM;
    *(float4*)&x[t * 4] = *(const float4*)&sep[t * 4];
}

// -------------------------------------------------- layernorm: X f32 -> Xn bf16
__global__ __launch_bounds__(256)
void k_ln(const float* __restrict__ X, bf16_t* __restrict__ Xn,
          const float* __restrict__ w, const float* __restrict__ bb,
          const int* __restrict__ cnt) {
    int b = blockIdx.y, n = blockIdx.x;
    int Nb = 1025 + cnt[b];
    if (n >= Nb) return;
    int t = threadIdx.x;
    const float* x = X + ((size_t)b * NMAX + n) * DIM;
    float4 v = *(const float4*)&x[t * 4];
    float s = v.x + v.y + v.z + v.w;
    float q = v.x * v.x + v.y * v.y + v.z * v.z + v.w * v.w;
    #pragma unroll
    for (int off = 32; off > 0; off >>= 1) {
        s += __shfl_xor(s, off);
        q += __shfl_xor(q, off);
    }
    __shared__ float ss[4], sq[4];
    int wave = t >> 6, lane = t & 63;
    if (lane == 0) { ss[wave] = s; sq[wave] = q; }
    __syncthreads();
    s = ss[0] + ss[1] + ss[2] + ss[3];
    q = sq[0] + sq[1] + sq[2] + sq[3];
    float mean = s * (1.0f / DIM);
    float var  = q * (1.0f / DIM) - mean * mean;
    float rstd = 1.0f / sqrtf(var + 1e-5f);
    float4 ww = *(const float4*)&w[t * 4];
    float4 b4 = *(const float4*)&bb[t * 4];
    ushort4 o;
    o.x = f2bf((v.x - mean) * rstd * ww.x + b4.x);
    o.y = f2bf((v.y - mean) * rstd * ww.y + b4.y);
    o.z = f2bf((v.z - mean) * rstd * ww.z + b4.z);
    o.w = f2bf((v.w - mean) * rstd * ww.w + b4.w);
    *(ushort4*)&(Xn + ((size_t)b * NMAX + n) * DIM)[t * 4] = o;
}

// =========================================== MFMA GEMM: A bf16 @ W f32 (cvt)
// C[b](rows x Nout) = A[b] @ W + bias. 128x128 tile, 4 waves, each 64x64.
// mfma_f32_16x16x32_bf16: A-frag [m=l16][k=quad*8+j] from row-major As,
// B-frag [n=l16][k=quad*8+j] from transposed Bs (validated by R3 attention).
// EPI 0=store, 1=gelu+store, 2=residual add (OutT=float).
template <int EPI, typename OutT>
__global__ __launch_bounds__(256)
void k_gemm_mfma(const bf16_t* __restrict__ A, size_t bsA, int ldA,
                 const float* __restrict__ W, int ldW, const float* __restrict__ bias,
                 OutT* __restrict__ Out, size_t bsO, int ldO,
                 int K, const int* __restrict__ cnt, int bound_add, int rows_phys) {
    int b = blockIdx.z;
    int bound = cnt[b] + bound_add;
    int tr = blockIdx.y * 128;
    if (tr >= bound) return;
    int tc = blockIdx.x * 128;

    __shared__ bf16_t As[128][40];   // [row][k], 32 k + 8 pad (80 B rows, 16B-aligned)
    __shared__ bf16_t Bs[128][40];   // [n][k] transposed

    int tid  = threadIdx.x;
    int wave = tid >> 6, lane = tid & 63;
    int quad = lane >> 4, l16 = lane & 15;
    int wr = (wave >> 1) * 64, wc = (wave & 1) * 64;

    f32x4 acc[4][4];
    #pragma unroll
    for (int mi = 0; mi < 4; ++mi)
        #pragma unroll
        for (int ni = 0; ni < 4; ++ni)
            acc[mi][ni] = (f32x4){0.f, 0.f, 0.f, 0.f};

    const bf16_t* Ab = A + (size_t)b * bsA;
    int ar = tid >> 1;              // A stage: row, 16 bf16 per thread
    int ac = (tid & 1) * 16;
    int bn  = tid & 127;            // B stage: output col; k-chunks bkc, bkc+2
    int bkc = tid >> 7;

    for (int k0 = 0; k0 < K; k0 += 32) {
        __syncthreads();
        {   // A: 128 rows x 32 k (bf16 direct)
            int row = tr + ar;
            bf16x8 v0 = (bf16x8){0,0,0,0,0,0,0,0};
            bf16x8 v1 = (bf16x8){0,0,0,0,0,0,0,0};
            if (row < rows_phys) {
                const bf16_t* ap = Ab + (size_t)row * ldA + k0 + ac;
                v0 = *(const bf16x8*)ap;
                v1 = *(const bf16x8*)(ap + 8);
            }
            *(bf16x8*)&As[ar][ac]     = v0;
            *(bf16x8*)&As[ar][ac + 8] = v1;
        }
        #pragma unroll
        for (int c0 = 0; c0 < 2; ++c0) {   // B: f32 load + cvt, transposed store
            int kk = (bkc + c0 * 2) * 8;
            const float* wp = W + (size_t)(k0 + kk) * ldW + tc + bn;
            bf16_t tmp[8];
            #pragma unroll
            for (int j = 0; j < 8; ++j)
                tmp[j] = f2bf(wp[(size_t)j * ldW]);
            *(bf16x8*)&Bs[bn][kk] = *(bf16x8*)tmp;
        }
        __syncthreads();

        bf16x8 af[4], bfr[4];
        #pragma unroll
        for (int mi = 0; mi < 4; ++mi)
            af[mi] = *(const bf16x8*)&As[wr + mi * 16 + l16][quad * 8];
        #pragma unroll
        for (int ni = 0; ni < 4; ++ni)
            bfr[ni] = *(const bf16x8*)&Bs[wc + ni * 16 + l16][quad * 8];
        #pragma unroll
        for (int mi = 0; mi < 4; ++mi)
            #pragma unroll
            for (int ni = 0; ni < 4; ++ni)
                acc[mi][ni] = __builtin_amdgcn_mfma_f32_16x16x32_bf16(
                    af[mi], bfr[ni], acc[mi][ni], 0, 0, 0);
    }

    OutT* Ob = Out + (size_t)b * bsO;
    #pragma unroll
    for (int ni = 0; ni < 4; ++ni) {
        int col = tc + wc + ni * 16 + l16;
        float bs = bias[col];
        #pragma unroll
        for (int mi = 0; mi < 4; ++mi) {
            int row0 = tr + wr + mi * 16 + quad * 4;
            #pragma unroll
            for (int r = 0; r < 4; ++r) {
                int row = row0 + r;
                if (row >= rows_phys) continue;
                float v = acc[mi][ni][r] + bs;
                if (EPI == 1) v = gelu_exact(v);
                OutT* op = Ob + (size_t)row * ldO + col;
                if (EPI == 2) v += *(const float*)op;   // OutT=float for EPI 2
                if (sizeof(OutT) == 2) *(bf16_t*)op = f2bf(v);
                else                   *(float*)op  = v;
            }
        }
    }
}

// =================================================== MFMA flash attention
__global__ __launch_bounds__(256)
void k_attn_mfma(const bf16_t* __restrict__ QKV, bf16_t* __restrict__ O,
                 const int* __restrict__ cnt) {
    int b = blockIdx.z, h = blockIdx.y;
    int Nb = 1025 + cnt[b];
    int qbase = blockIdx.x * 64;
    if (qbase >= Nb) return;

    __shared__ bf16_t Kt[32][264];
    __shared__ bf16_t Vt[256][40];
    __shared__ bf16_t Pt[4][16][40];

    int tid  = threadIdx.x;
    int wave = tid >> 6, lane = tid & 63;
    int quad = lane >> 4, l16 = lane & 15;

    int qrow  = qbase + wave * 16 + l16;
    int qrowc = qrow < NMAX ? qrow : NMAX - 1;
    const bf16_t* Qp = QKV + (size_t)b * NMAX * 3072 + (size_t)qrowc * 3072 + h * HD;
    bf16x8 qf[8];
    #pragma unroll
    for (int c = 0; c < 8; ++c)
        qf[c] = *(const bf16x8*)(Qp + c * 32 + quad * 8);

    f32x4 Oacc[16];
    #pragma unroll
    for (int n = 0; n < 16; ++n) Oacc[n] = (f32x4){0.f, 0.f, 0.f, 0.f};
    float l[4] = {0.f, 0.f, 0.f, 0.f};

    const bf16_t* Kg = QKV + (size_t)b * NMAX * 3072 + 1024 + h * HD;
    const bf16_t* Vg = QKV + (size_t)b * NMAX * 3072 + 2048 + h * HD;

    int krow_s = tid >> 3;
    int kd_s   = (tid & 7) * 8;
    int vd_s   = (tid >> 3) * 8;
    int vr_s   = (tid & 7) * 4;

    for (int kt = 0; kt < Nb; kt += 32) {
        __syncthreads();
        #pragma unroll
        for (int i = 0; i < 4; ++i) {
            int gk = kt + krow_s;
            int d  = kd_s + i * 64;
            bf16x8 v = (bf16x8){0,0,0,0,0,0,0,0};
            if (gk < Nb) v = *(const bf16x8*)(Kg + (size_t)gk * 3072 + d);
            *(bf16x8*)&Kt[krow_s][d] = v;
        }
        {
            bf16x8 vv[4];
            #pragma unroll
            for (int r = 0; r < 4; ++r) {
                int gk = kt + vr_s + r;
                vv[r] = (bf16x8){0,0,0,0,0,0,0,0};
                if (gk < Nb) vv[r] = *(const bf16x8*)(Vg + (size_t)gk * 3072 + vd_s);
            }
            #pragma unroll
            for (int j = 0; j < 8; ++j) {
                ushort4 pk;
                pk.x = (unsigned short)vv[0][j];
                pk.y = (unsigned short)vv[1][j];
                pk.z = (unsigned short)vv[2][j];
                pk.w = (unsigned short)vv[3][j];
                *(ushort4*)&Vt[vd_s + j][vr_s] = pk;
            }
        }
        __syncthreads();

        f32x4 c0 = (f32x4){0.f,0.f,0.f,0.f}, c1 = (f32x4){0.f,0.f,0.f,0.f};
        #pragma unroll
        for (int c = 0; c < 8; ++c) {
            bf16x8 kb0 = *(const bf16x8*)&Kt[l16     ][c * 32 + quad * 8];
            bf16x8 kb1 = *(const bf16x8*)&Kt[l16 + 16][c * 32 + quad * 8];
            c0 = __builtin_amdgcn_mfma_f32_16x16x32_bf16(qf[c], kb0, c0, 0, 0, 0);
            c1 = __builtin_amdgcn_mfma_f32_16x16x32_bf16(qf[c], kb1, c1, 0, 0, 0);
        }
        float ls[4];
        #pragma unroll
        for (int r = 0; r < 4; ++r) {
            float p0 = (kt + l16      < Nb) ? __expf(c0[r] * 0.0625f) : 0.f;
            float p1 = (kt + 16 + l16 < Nb) ? __expf(c1[r] * 0.0625f) : 0.f;
            Pt[wave][quad * 4 + r][l16]      = f2bf(p0);
            Pt[wave][quad * 4 + r][l16 + 16] = f2bf(p1);
            ls[r] = p0 + p1;
        }
        #pragma unroll
        for (int off = 1; off < 16; off <<= 1)
            #pragma unroll
            for (int r = 0; r < 4; ++r)
                ls[r] += __shfl_xor(ls[r], off);
        #pragma unroll
        for (int r = 0; r < 4; ++r) l[r] += ls[r];

        bf16x8 pa = *(const bf16x8*)&Pt[wave][l16][quad * 8];
        #pragma unroll
        for (int n = 0; n < 16; ++n) {
            bf16x8 vb = *(const bf16x8*)&Vt[n * 16 + l16][quad * 8];
            Oacc[n] = __builtin_amdgcn_mfma_f32_16x16x32_bf16(pa, vb, Oacc[n], 0, 0, 0);
        }
    }

    float inv[4];
    #pragma unroll
    for (int r = 0; r < 4; ++r) inv[r] = 1.0f / l[r];
    bf16_t* Op = O + (size_t)b * NMAX * DIM + h * HD;
    #pragma unroll
    for (int r = 0; r < 4; ++r) {
        int row = qbase + wave * 16 + quad * 4 + r;
        if (row < Nb) {
            bf16_t* op = Op + (size_t)row * DIM;
            #pragma unroll
            for (int n = 0; n < 16; ++n)
                op[n * 16 + l16] = f2bf(Oacc[n][r] * inv[r]);
        }
    }
}

// ---------------------------------------------------------------- output
__global__ __launch_bounds__(256)
void k_out(const float* __restrict__ X, const float* __restrict__ emb,
           const int* __restrict__ cnt, float* __restrict__ out) {
    int b = blockIdx.y, n = blockIdx.x, t = threadIdx.x;
    const float* s = (cnt[b] > 0) ? X + ((size_t)b * NMAX + n) * DIM
                                  : emb + ((size_t)b * NQ + n) * DIM;
    *(float4*)&out[((size_t)b * NQ + n) * DIM + t * 4] = *(const float4*)&s[t * 4];
}

// ============================================================== launch
extern "C" void kernel_launch(void* const* d_in, const int* in_sizes, int n_in,
                              void* d_out, int out_size, void* d_ws, size_t ws_size,
                              hipStream_t stream) {
    const float* emb    = (const float*)d_in[0];
    const float* depth  = (const float*)d_in[1];
    const int*   mask   = (const int*)d_in[2];
    const float* gauss  = (const float*)d_in[5];
    const float* d2f_w1 = (const float*)d_in[6];
    const float* d2f_b1 = (const float*)d_in[7];
    const float* d2f_w2 = (const float*)d_in[8];
    const float* d2f_b2 = (const float*)d_in[9];
    const float* sep    = (const float*)d_in[10];
    const float* ln1_w  = (const float*)d_in[11];
    const float* ln1_b  = (const float*)d_in[12];
    const float* qkv_w  = (const float*)d_in[13];
    const float* qkv_b  = (const float*)d_in[14];
    const float* proj_w = (const float*)d_in[15];
    const float* proj_b = (const float*)d_in[16];
    const float* ln2_w  = (const float*)d_in[17];
    const float* ln2_b  = (const float*)d_in[18];
    const float* mlp_w1 = (const float*)d_in[19];
    const float* mlp_b1 = (const float*)d_in[20];
    const float* mlp_w2 = (const float*)d_in[21];
    const float* mlp_b2 = (const float*)d_in[22];
    float* out = (float*)d_out;

    char* wsb = (char*)d_ws;
    int*    cnt   = (int*)wsb;
    int*    pidx  = (int*)(wsb + 256);
    float*  zbias = (float*)(wsb + 37120);
    float*  X     = (float*)(wsb + 41216);
    bf16_t* Xn    = (bf16_t*)(wsb + 41216 + (size_t)NBATCH * NMAX * DIM * 4);
    bf16_t* Qb    = (bf16_t*)(wsb + 41216 + (size_t)NBATCH * NMAX * DIM * 6);
    if (ws_size < (size_t)163668224) return;

    k_compact<<<NBATCH, 256, 0, stream>>>(mask, cnt, pidx);
    k_zerobias<<<4, 256, 0, stream>>>(zbias);
    k_init_query<<<dim3(NQ, NBATCH), 256, 0, stream>>>(emb, gauss, X);
    k_prompt_h<<<dim3(MASKN, NBATCH), 256, 0, stream>>>(depth, d2f_w1, d2f_b1, cnt, pidx, Qb);
    k_gemm_mfma<0, float><<<dim3(8, 18, NBATCH), 256, 0, stream>>>(
        Qb, (size_t)MASKN * 512, 512, d2f_w2, DIM, d2f_b2,
        X + (size_t)1025 * DIM, (size_t)NMAX * DIM, DIM, 512, cnt, 0, MASKN);
    k_pe_prompt<<<dim3(MASKN, NBATCH), 256, 0, stream>>>(gauss, cnt, pidx, X);

    for (int i = 0; i < 2; ++i) {
        k_sep<<<NBATCH, 256, 0, stream>>>(X, sep + (size_t)i * DIM);
        k_ln<<<dim3(NMAX, NBATCH), 256, 0, stream>>>(X, Xn, ln1_w + i * DIM, ln1_b + i * DIM, cnt);
        k_gemm_mfma<0, bf16_t><<<dim3(24, 27, NBATCH), 256, 0, stream>>>(
            Xn, (size_t)NMAX * DIM, DIM,
            qkv_w + (size_t)i * DIM * 3072, 3072, qkv_b + (size_t)i * 3072,
            Qb, (size_t)NMAX * 3072, 3072, DIM, cnt, 1025, NMAX);
        k_attn_mfma<<<dim3(53, NHEAD, NBATCH), 256, 0, stream>>>(Qb, Xn, cnt);
        k_gemm_mfma<2, float><<<dim3(8, 27, NBATCH), 256, 0, stream>>>(
            Xn, (size_t)NMAX * DIM, DIM,
            proj_w + (size_t)i * DIM * DIM, DIM, proj_b + (size_t)i * DIM,
            X, (size_t)NMAX * DIM, DIM, DIM, cnt, 1025, NMAX);
        k_ln<<<dim3(NMAX, NBATCH), 256, 0, stream>>>(X, Xn, ln2_w + i * DIM, ln2_b + i * DIM, cnt);
        for (int c = 0; c < 2; ++c) {
            k_gemm_mfma<1, bf16_t><<<dim3(16, 27, NBATCH), 256, 0, stream>>>(
                Xn, (size_t)NMAX * DIM, DIM,
                mlp_w1 + (size_t)i * DIM * 4096 + c * 2048, 4096,
                mlp_b1 + (size_t)i * 4096 + c * 2048,
                Qb, (size_t)NMAX * 2048, 2048, DIM, cnt, 1025, NMAX);
            k_gemm_mfma<2, float><<<dim3(8, 27, NBATCH), 256, 0, stream>>>(
                Qb, (size_t)NMAX * 2048, 2048,
                mlp_w2 + (size_t)i * 4096 * DIM + (size_t)c * 2048 * DIM, DIM,
                (c == 0) ? (mlp_b2 + (size_t)i * DIM) : zbias,
                X, (size_t)NMAX * DIM, DIM, 2048, cnt, 1025, NMAX);
        }
    }

    k_out<<<dim3(NQ, NBATCH), 256, 0, stream>>>(X, emb, cnt, out);
    (void)in_sizes; (void)n_in; (void)out_size;
}

// Round 5
// 1719.625 us; speedup vs baseline: 13.4039x; 1.1517x over previous
//
#include <hip/hip_runtime.h>
#include <math.h>

#define NBATCH 4
#define DIM    1024
#define NHEAD  4
#define HD     256
#define NQ     1024
#define MASKN  2304           // 48*48
#define NMAX   3329           // 1024 query + 1 sep + 2304 max prompts
#define TWO_PI 6.283185307179586f

typedef unsigned short bf16_t;
typedef short bf16x8 __attribute__((ext_vector_type(8)));
typedef float f32x4  __attribute__((ext_vector_type(4)));

__device__ __forceinline__ float gelu_exact(float x) {
    return 0.5f * x * (1.0f + erff(x * 0.70710678118654752f));
}
__device__ __forceinline__ float bf2f(bf16_t h) {
    return __uint_as_float((unsigned)h << 16);
}
__device__ __forceinline__ bf16_t f2bf(float f) {   // round-to-nearest-even
    unsigned u = __float_as_uint(f);
    return (bf16_t)((u + 0x7FFFu + ((u >> 16) & 1u)) >> 16);
}

// ---------------------------------------------------------------- compaction
__global__ __launch_bounds__(256)
void k_compact(const int* __restrict__ mask, int* __restrict__ cnt, int* __restrict__ pidx) {
    int b = blockIdx.x;
    __shared__ int sc;
    if (threadIdx.x == 0) sc = 0;
    __syncthreads();
    for (int c = threadIdx.x; c < MASKN; c += blockDim.x)
        if (mask[b * MASKN + c] > 0) {
            int p = atomicAdd(&sc, 1);
            pidx[b * MASKN + p] = c;
        }
    __syncthreads();
    if (threadIdx.x == 0) cnt[b] = sc;
}

__global__ __launch_bounds__(256)
void k_zerobias(float* __restrict__ z) {
    z[blockIdx.x * 256 + threadIdx.x] = 0.f;
}

// ---------------------------------- weight transpose-convert: W(KxN f32)->Wt(NxK bf16)
__global__ __launch_bounds__(256)
void k_wt(const float* __restrict__ W, bf16_t* __restrict__ Wt, int K, int N) {
    __shared__ float T[64][65];
    int n0 = blockIdx.x * 64, k0 = blockIdx.y * 64;
    int tid = threadIdx.x;
    int lr = tid >> 4, lc = (tid & 15) * 4;
    #pragma unroll
    for (int i = 0; i < 4; ++i) {
        float4 v = *(const float4*)&W[(size_t)(k0 + lr + i * 16) * N + n0 + lc];
        T[lr + i * 16][lc + 0] = v.x; T[lr + i * 16][lc + 1] = v.y;
        T[lr + i * 16][lc + 2] = v.z; T[lr + i * 16][lc + 3] = v.w;
    }
    __syncthreads();
    int on = tid >> 2, ok = (tid & 3) * 16;
    bf16_t tmp[16];
    #pragma unroll
    for (int j = 0; j < 16; ++j) tmp[j] = f2bf(T[ok + j][on]);
    bf16_t* op = Wt + (size_t)(n0 + on) * K + k0 + ok;
    *(bf16x8*)op       = *(bf16x8*)&tmp[0];
    *(bf16x8*)(op + 8) = *(bf16x8*)&tmp[8];
}

// ------------------------------------------------- query tokens: emb + PE (f32 X)
__global__ __launch_bounds__(256)
void k_init_query(const float* __restrict__ emb, const float* __restrict__ gauss,
                  float* __restrict__ X) {
    int b = blockIdx.y, n = blockIdx.x, t = threadIdx.x;
    float fx = 2.0f * (((n & 31) + 0.5f) / 32.0f) - 1.0f;
    float fy = 2.0f * (((n >> 5) + 0.5f) / 32.0f) - 1.0f;
    const float* e = emb + ((size_t)b * NQ + n) * DIM;
    float* x = X + ((size_t)b * NMAX + n) * DIM;
    for (int d = t; d < 512; d += 256) {
        float ang = TWO_PI * (fx * gauss[d] + fy * gauss[512 + d]);
        float sn, cs; sincosf(ang, &sn, &cs);
        x[d]       = e[d] + sn;
        x[d + 512] = e[d + 512] + cs;
    }
}

// --------------------------------- prompt hidden: gelu(d*w1+b1) (M x 512) bf16
__global__ __launch_bounds__(256)
void k_prompt_h(const float* __restrict__ depth, const float* __restrict__ w1,
                const float* __restrict__ b1, const int* __restrict__ cnt,
                const int* __restrict__ pidx, bf16_t* __restrict__ Hp) {
    int b = blockIdx.y, s = blockIdx.x, t = threadIdx.x;
    bf16_t* hp = Hp + ((size_t)b * MASKN + s) * 512;
    if (s >= cnt[b]) { hp[t] = 0; hp[t + 256] = 0; return; }
    int cell = pidx[b * MASKN + s];
    float d = depth[b * MASKN + cell];
    for (int j = t; j < 512; j += 256)
        hp[j] = f2bf(gelu_exact(fmaf(d, w1[j], b1[j])));
}

// ------------------------------------------ add prompt PE into X rows (f32)
__global__ __launch_bounds__(256)
void k_pe_prompt(const float* __restrict__ gauss, const int* __restrict__ cnt,
                 const int* __restrict__ pidx, float* __restrict__ X) {
    int b = blockIdx.y, s = blockIdx.x, t = threadIdx.x;
    if (s >= cnt[b]) return;
    int cell = pidx[b * MASKN + s];
    int r = cell / 48, c = cell % 48;
    float fx = 2.0f * ((c + 0.5f) / 48.0f) - 1.0f;
    float fy = 2.0f * ((r + 0.5f) / 48.0f) - 1.0f;
    float* x = X + ((size_t)b * NMAX + 1025 + s) * DIM;
    for (int d = t; d < 512; d += 256) {
        float ang = TWO_PI * (fx * gauss[d] + fy * gauss[512 + d]);
        float sn, cs; sincosf(ang, &sn, &cs);
        x[d]       += sn;
        x[d + 512] += cs;
    }
}

// ---------------------------------------------------------------- sep token
__global__ __launch_bounds__(256)
void k_sep(float* __restrict__ X, const float* __restrict__ sep) {
    int b = blockIdx.x, t = threadIdx.x;
    float* x = X + ((size_t)b * NMAX + 1024) * DIM;
    *(float4*)&x[t * 4] = *(const float4*)&sep[t * 4];
}

// -------------------------------------------------- layernorm: X f32 -> Xn bf16
__global__ __launch_bounds__(256)
void k_ln(const float* __restrict__ X, bf16_t* __restrict__ Xn,
          const float* __restrict__ w, const float* __restrict__ bb,
          const int* __restrict__ cnt) {
    int b = blockIdx.y, n = blockIdx.x;
    int Nb = 1025 + cnt[b];
    if (n >= Nb) return;
    int t = threadIdx.x;
    const float* x = X + ((size_t)b * NMAX + n) * DIM;
    float4 v = *(const float4*)&x[t * 4];
    float s = v.x + v.y + v.z + v.w;
    float q = v.x * v.x + v.y * v.y + v.z * v.z + v.w * v.w;
    #pragma unroll
    for (int off = 32; off > 0; off >>= 1) {
        s += __shfl_xor(s, off);
        q += __shfl_xor(q, off);
    }
    __shared__ float ss[4], sq[4];
    int wave = t >> 6, lane = t & 63;
    if (lane == 0) { ss[wave] = s; sq[wave] = q; }
    __syncthreads();
    s = ss[0] + ss[1] + ss[2] + ss[3];
    q = sq[0] + sq[1] + sq[2] + sq[3];
    float mean = s * (1.0f / DIM);
    float var  = q * (1.0f / DIM) - mean * mean;
    float rstd = 1.0f / sqrtf(var + 1e-5f);
    float4 ww = *(const float4*)&w[t * 4];
    float4 b4 = *(const float4*)&bb[t * 4];
    ushort4 o;
    o.x = f2bf((v.x - mean) * rstd * ww.x + b4.x);
    o.y = f2bf((v.y - mean) * rstd * ww.y + b4.y);
    o.z = f2bf((v.z - mean) * rstd * ww.z + b4.z);
    o.w = f2bf((v.w - mean) * rstd * ww.w + b4.w);
    *(ushort4*)&(Xn + ((size_t)b * NMAX + n) * DIM)[t * 4] = o;
}

// ================================ MFMA GEMM: A bf16 @ Wt bf16 (pre-transposed)
// C[b](rows x Nout) = A[b] @ Wt^T + bias. 128x128 tile, BK=64, 4 waves x 64x64.
// Wt is [n][k] row-major with row stride ldWt. EPI 0=store,1=gelu,2=residual.
template <int EPI, typename OutT>
__global__ __launch_bounds__(256)
void k_gemm_bt(const bf16_t* __restrict__ A, size_t bsA, int ldA,
               const bf16_t* __restrict__ Wt, int ldWt, const float* __restrict__ bias,
               OutT* __restrict__ Out, size_t bsO, int ldO,
               int K, const int* __restrict__ cnt, int bound_add, int rows_phys) {
    int b = blockIdx.z;
    int bound = cnt[b] + bound_add;
    int tr = blockIdx.y * 128;
    if (tr >= bound) return;
    int tc = blockIdx.x * 128;

    __shared__ bf16_t As[128][72];   // 64 k + 8 pad (144 B rows -> 2-way free)
    __shared__ bf16_t Bs[128][72];

    int tid  = threadIdx.x;
    int wave = tid >> 6, lane = tid & 63;
    int quad = lane >> 4, l16 = lane & 15;
    int wr = (wave >> 1) * 64, wc = (wave & 1) * 64;

    f32x4 acc[4][4];
    #pragma unroll
    for (int mi = 0; mi < 4; ++mi)
        #pragma unroll
        for (int ni = 0; ni < 4; ++ni)
            acc[mi][ni] = (f32x4){0.f, 0.f, 0.f, 0.f};

    const bf16_t* Ab = A + (size_t)b * bsA;
    int sr = tid >> 1;              // staged row 0..127
    int sc = (tid & 1) * 32;        // k-half

    for (int k0 = 0; k0 < K; k0 += 64) {
        __syncthreads();
        {   // A: 128 rows x 64 k
            int row = tr + sr;
            bf16x8 v[4];
            #pragma unroll
            for (int j = 0; j < 4; ++j) v[j] = (bf16x8){0,0,0,0,0,0,0,0};
            if (row < rows_phys) {
                const bf16_t* ap = Ab + (size_t)row * ldA + k0 + sc;
                #pragma unroll
                for (int j = 0; j < 4; ++j) v[j] = *(const bf16x8*)(ap + j * 8);
            }
            #pragma unroll
            for (int j = 0; j < 4; ++j) *(bf16x8*)&As[sr][sc + j * 8] = v[j];
        }
        {   // B: 128 n-rows x 64 k from Wt
            const bf16_t* bp = Wt + (size_t)(tc + sr) * ldWt + k0 + sc;
            #pragma unroll
            for (int j = 0; j < 4; ++j)
                *(bf16x8*)&Bs[sr][sc + j * 8] = *(const bf16x8*)(bp + j * 8);
        }
        __syncthreads();

        #pragma unroll
        for (int half = 0; half < 2; ++half) {
            int ko = half * 32 + quad * 8;
            bf16x8 af[4], bfr[4];
            #pragma unroll
            for (int mi = 0; mi < 4; ++mi)
                af[mi] = *(const bf16x8*)&As[wr + mi * 16 + l16][ko];
            #pragma unroll
            for (int ni = 0; ni < 4; ++ni)
                bfr[ni] = *(const bf16x8*)&Bs[wc + ni * 16 + l16][ko];
            #pragma unroll
            for (int mi = 0; mi < 4; ++mi)
                #pragma unroll
                for (int ni = 0; ni < 4; ++ni)
                    acc[mi][ni] = __builtin_amdgcn_mfma_f32_16x16x32_bf16(
                        af[mi], bfr[ni], acc[mi][ni], 0, 0, 0);
        }
    }

    OutT* Ob = Out + (size_t)b * bsO;
    #pragma unroll
    for (int ni = 0; ni < 4; ++ni) {
        int col = tc + wc + ni * 16 + l16;
        float bs = bias[col];
        #pragma unroll
        for (int mi = 0; mi < 4; ++mi) {
            int row0 = tr + wr + mi * 16 + quad * 4;
            #pragma unroll
            for (int r = 0; r < 4; ++r) {
                int row = row0 + r;
                if (row >= rows_phys) continue;
                float v = acc[mi][ni][r] + bs;
                if (EPI == 1) v = gelu_exact(v);
                OutT* op = Ob + (size_t)row * ldO + col;
                if (EPI == 2) v += *(const float*)op;   // OutT=float for EPI 2
                if (sizeof(OutT) == 2) *(bf16_t*)op = f2bf(v);
                else                   *(float*)op  = v;
            }
        }
    }
}

// =================================================== MFMA flash attention
__global__ __launch_bounds__(256)
void k_attn_mfma(const bf16_t* __restrict__ QKV, bf16_t* __restrict__ O,
                 const int* __restrict__ cnt) {
    int b = blockIdx.z, h = blockIdx.y;
    int Nb = 1025 + cnt[b];
    int qbase = blockIdx.x * 64;
    if (qbase >= Nb) return;

    __shared__ bf16_t Kt[32][264];
    __shared__ bf16_t Vt[256][40];
    __shared__ bf16_t Pt[4][16][40];

    int tid  = threadIdx.x;
    int wave = tid >> 6, lane = tid & 63;
    int quad = lane >> 4, l16 = lane & 15;

    int qrow  = qbase + wave * 16 + l16;
    int qrowc = qrow < NMAX ? qrow : NMAX - 1;
    const bf16_t* Qp = QKV + (size_t)b * NMAX * 3072 + (size_t)qrowc * 3072 + h * HD;
    bf16x8 qf[8];
    #pragma unroll
    for (int c = 0; c < 8; ++c)
        qf[c] = *(const bf16x8*)(Qp + c * 32 + quad * 8);

    f32x4 Oacc[16];
    #pragma unroll
    for (int n = 0; n < 16; ++n) Oacc[n] = (f32x4){0.f, 0.f, 0.f, 0.f};
    float l[4] = {0.f, 0.f, 0.f, 0.f};

    const bf16_t* Kg = QKV + (size_t)b * NMAX * 3072 + 1024 + h * HD;
    const bf16_t* Vg = QKV + (size_t)b * NMAX * 3072 + 2048 + h * HD;

    int krow_s = tid >> 3;
    int kd_s   = (tid & 7) * 8;
    int vd_s   = (tid >> 3) * 8;
    int vr_s   = (tid & 7) * 4;

    for (int kt = 0; kt < Nb; kt += 32) {
        __syncthreads();
        #pragma unroll
        for (int i = 0; i < 4; ++i) {
            int gk = kt + krow_s;
            int d  = kd_s + i * 64;
            bf16x8 v = (bf16x8){0,0,0,0,0,0,0,0};
            if (gk < Nb) v = *(const bf16x8*)(Kg + (size_t)gk * 3072 + d);
            *(bf16x8*)&Kt[krow_s][d] = v;
        }
        {
            bf16x8 vv[4];
            #pragma unroll
            for (int r = 0; r < 4; ++r) {
                int gk = kt + vr_s + r;
                vv[r] = (bf16x8){0,0,0,0,0,0,0,0};
                if (gk < Nb) vv[r] = *(const bf16x8*)(Vg + (size_t)gk * 3072 + vd_s);
            }
            #pragma unroll
            for (int j = 0; j < 8; ++j) {
                ushort4 pk;
                pk.x = (unsigned short)vv[0][j];
                pk.y = (unsigned short)vv[1][j];
                pk.z = (unsigned short)vv[2][j];
                pk.w = (unsigned short)vv[3][j];
                *(ushort4*)&Vt[vd_s + j][vr_s] = pk;
            }
        }
        __syncthreads();

        f32x4 c0 = (f32x4){0.f,0.f,0.f,0.f}, c1 = (f32x4){0.f,0.f,0.f,0.f};
        #pragma unroll
        for (int c = 0; c < 8; ++c) {
            bf16x8 kb0 = *(const bf16x8*)&Kt[l16     ][c * 32 + quad * 8];
            bf16x8 kb1 = *(const bf16x8*)&Kt[l16 + 16][c * 32 + quad * 8];
            c0 = __builtin_amdgcn_mfma_f32_16x16x32_bf16(qf[c], kb0, c0, 0, 0, 0);
            c1 = __builtin_amdgcn_mfma_f32_16x16x32_bf16(qf[c], kb1, c1, 0, 0, 0);
        }
        float ls[4];
        #pragma unroll
        for (int r = 0; r < 4; ++r) {
            float p0 = (kt + l16      < Nb) ? __expf(c0[r] * 0.0625f) : 0.f;
            float p1 = (kt + 16 + l16 < Nb) ? __expf(c1[r] * 0.0625f) : 0.f;
            Pt[wave][quad * 4 + r][l16]      = f2bf(p0);
            Pt[wave][quad * 4 + r][l16 + 16] = f2bf(p1);
            ls[r] = p0 + p1;
        }
        #pragma unroll
        for (int off = 1; off < 16; off <<= 1)
            #pragma unroll
            for (int r = 0; r < 4; ++r)
                ls[r] += __shfl_xor(ls[r], off);
        #pragma unroll
        for (int r = 0; r < 4; ++r) l[r] += ls[r];

        bf16x8 pa = *(const bf16x8*)&Pt[wave][l16][quad * 8];
        #pragma unroll
        for (int n = 0; n < 16; ++n) {
            bf16x8 vb = *(const bf16x8*)&Vt[n * 16 + l16][quad * 8];
            Oacc[n] = __builtin_amdgcn_mfma_f32_16x16x32_bf16(pa, vb, Oacc[n], 0, 0, 0);
        }
    }

    float inv[4];
    #pragma unroll
    for (int r = 0; r < 4; ++r) inv[r] = 1.0f / l[r];
    bf16_t* Op = O + (size_t)b * NMAX * DIM + h * HD;
    #pragma unroll
    for (int r = 0; r < 4; ++r) {
        int row = qbase + wave * 16 + quad * 4 + r;
        if (row < Nb) {
            bf16_t* op = Op + (size_t)row * DIM;
            #pragma unroll
            for (int n = 0; n < 16; ++n)
                op[n * 16 + l16] = f2bf(Oacc[n][r] * inv[r]);
        }
    }
}

// ---------------------------------------------------------------- output
__global__ __launch_bounds__(256)
void k_out(const float* __restrict__ X, const float* __restrict__ emb,
           const int* __restrict__ cnt, float* __restrict__ out) {
    int b = blockIdx.y, n = blockIdx.x, t = threadIdx.x;
    const float* s = (cnt[b] > 0) ? X + ((size_t)b * NMAX + n) * DIM
                                  : emb + ((size_t)b * NQ + n) * DIM;
    *(float4*)&out[((size_t)b * NQ + n) * DIM + t * 4] = *(const float4*)&s[t * 4];
}

// ============================================================== launch
extern "C" void kernel_launch(void* const* d_in, const int* in_sizes, int n_in,
                              void* d_out, int out_size, void* d_ws, size_t ws_size,
                              hipStream_t stream) {
    const float* emb    = (const float*)d_in[0];
    const float* depth  = (const float*)d_in[1];
    const int*   mask   = (const int*)d_in[2];
    const float* gauss  = (const float*)d_in[5];
    const float* d2f_w1 = (const float*)d_in[6];
    const float* d2f_b1 = (const float*)d_in[7];
    const float* d2f_w2 = (const float*)d_in[8];
    const float* d2f_b2 = (const float*)d_in[9];
    const float* sep    = (const float*)d_in[10];
    const float* ln1_w  = (const float*)d_in[11];
    const float* ln1_b  = (const float*)d_in[12];
    const float* qkv_w  = (const float*)d_in[13];
    const float* qkv_b  = (const float*)d_in[14];
    const float* proj_w = (const float*)d_in[15];
    const float* proj_b = (const float*)d_in[16];
    const float* ln2_w  = (const float*)d_in[17];
    const float* ln2_b  = (const float*)d_in[18];
    const float* mlp_w1 = (const float*)d_in[19];
    const float* mlp_b1 = (const float*)d_in[20];
    const float* mlp_w2 = (const float*)d_in[21];
    const float* mlp_b2 = (const float*)d_in[22];
    float* out = (float*)d_out;

    // ws layout: [cnt|pidx|zbias 41216][X f32 54.5M][Xn bf16 27.3M][Qb 81.8M]
    //            [Wt_qkv 6.29M][Wt_proj 2.10M][Wt_m1 8.39M][Wt_m2 8.39M] = 188,834,048 B
    char* wsb = (char*)d_ws;
    int*    cnt   = (int*)wsb;
    int*    pidx  = (int*)(wsb + 256);
    float*  zbias = (float*)(wsb + 37120);
    float*  X     = (float*)(wsb + 41216);
    bf16_t* Xn    = (bf16_t*)(wsb + 54583552);
    bf16_t* Qb    = (bf16_t*)(wsb + 81854720);
    bf16_t* Wt_qkv = (bf16_t*)(wsb + 163668224);   // also d2f slot in prologue
    bf16_t* Wt_proj= (bf16_t*)(wsb + 169959680);
    bf16_t* Wt_m1  = (bf16_t*)(wsb + 172056832);
    bf16_t* Wt_m2  = (bf16_t*)(wsb + 180445440);
    if (ws_size < (size_t)188834048) return;   // clean fail instead of OOB crash

    k_compact<<<NBATCH, 256, 0, stream>>>(mask, cnt, pidx);
    k_zerobias<<<4, 256, 0, stream>>>(zbias);
    k_init_query<<<dim3(NQ, NBATCH), 256, 0, stream>>>(emb, gauss, X);
    k_prompt_h<<<dim3(MASKN, NBATCH), 256, 0, stream>>>(depth, d2f_w1, d2f_b1, cnt, pidx, Qb);
    // d2f_w2 (512x1024) -> Wt (1024x512) in qkv slot
    k_wt<<<dim3(16, 8), 256, 0, stream>>>(d2f_w2, Wt_qkv, 512, DIM);
    k_gemm_bt<0, float><<<dim3(8, 18, NBATCH), 256, 0, stream>>>(
        Qb, (size_t)MASKN * 512, 512, Wt_qkv, 512, d2f_b2,
        X + (size_t)1025 * DIM, (size_t)NMAX * DIM, DIM, 512, cnt, 0, MASKN);
    k_pe_prompt<<<dim3(MASKN, NBATCH), 256, 0, stream>>>(gauss, cnt, pidx, X);

    for (int i = 0; i < 2; ++i) {
        // convert this block's weights
        k_wt<<<dim3(48, 16), 256, 0, stream>>>(qkv_w  + (size_t)i * DIM * 3072, Wt_qkv,  DIM, 3072);
        k_wt<<<dim3(16, 16), 256, 0, stream>>>(proj_w + (size_t)i * DIM * DIM,  Wt_proj, DIM, DIM);
        k_wt<<<dim3(64, 16), 256, 0, stream>>>(mlp_w1 + (size_t)i * DIM * 4096, Wt_m1,   DIM, 4096);
        k_wt<<<dim3(16, 64), 256, 0, stream>>>(mlp_w2 + (size_t)i * 4096 * DIM, Wt_m2,   4096, DIM);

        k_sep<<<NBATCH, 256, 0, stream>>>(X, sep + (size_t)i * DIM);
        k_ln<<<dim3(NMAX, NBATCH), 256, 0, stream>>>(X, Xn, ln1_w + i * DIM, ln1_b + i * DIM, cnt);
        k_gemm_bt<0, bf16_t><<<dim3(24, 27, NBATCH), 256, 0, stream>>>(
            Xn, (size_t)NMAX * DIM, DIM, Wt_qkv, DIM, qkv_b + (size_t)i * 3072,
            Qb, (size_t)NMAX * 3072, 3072, DIM, cnt, 1025, NMAX);
        k_attn_mfma<<<dim3(53, NHEAD, NBATCH), 256, 0, stream>>>(Qb, Xn, cnt);
        k_gemm_bt<2, float><<<dim3(8, 27, NBATCH), 256, 0, stream>>>(
            Xn, (size_t)NMAX * DIM, DIM, Wt_proj, DIM, proj_b + (size_t)i * DIM,
            X, (size_t)NMAX * DIM, DIM, DIM, cnt, 1025, NMAX);
        k_ln<<<dim3(NMAX, NBATCH), 256, 0, stream>>>(X, Xn, ln2_w + i * DIM, ln2_b + i * DIM, cnt);
        for (int c = 0; c < 2; ++c) {
            k_gemm_bt<1, bf16_t><<<dim3(16, 27, NBATCH), 256, 0, stream>>>(
                Xn, (size_t)NMAX * DIM, DIM,
                Wt_m1 + (size_t)c * 2048 * DIM, DIM,
                mlp_b1 + (size_t)i * 4096 + c * 2048,
                Qb, (size_t)NMAX * 2048, 2048, DIM, cnt, 1025, NMAX);
            k_gemm_bt<2, float><<<dim3(8, 27, NBATCH), 256, 0, stream>>>(
                Qb, (size_t)NMAX * 2048, 2048,
                Wt_m2 + (size_t)c * 2048, 4096,
                (c == 0) ? (mlp_b2 + (size_t)i * DIM) : zbias,
                X, (size_t)NMAX * DIM, DIM, 2048, cnt, 1025, NMAX);
        }
    }

    k_out<<<dim3(NQ, NBATCH), 256, 0, stream>>>(X, emb, cnt, out);
    (void)in_sizes; (void)n_in; (void)out_size;
}